// Round 20
// baseline (28.347 us; speedup 1.0000x reference)
//
#include <hip/hip_runtime.h>

#define D 64
#define L 10
#define C 256
#define G 4
#define SWB 72  // bf16 LDS row stride in shorts (144 B, 16B-aligned)
#define ST 66   // s2 row stride in float2 (528 B)

typedef __attribute__((ext_vector_type(8))) short bf16x8;
typedef __attribute__((ext_vector_type(4))) short short4v;
typedef __attribute__((ext_vector_type(4))) float f32x4;

__device__ inline short f2bf(float f) {
  unsigned u = __float_as_uint(f);
  u = (u + 0x7FFFu + ((u >> 16) & 1u)) >> 16;
  return (short)u;
}
__device__ inline float4 add3(float4 a, float4 b, float4 c) {
  return make_float4(a.x + b.x + c.x, a.y + b.y + c.y, a.z + b.z + c.z, a.w + b.w + c.w);
}
__device__ inline short4v f2bf4(float4 a) {
  short4v r;
  r[0] = f2bf(a.x); r[1] = f2bf(a.y); r[2] = f2bf(a.z); r[3] = f2bf(a.w);
  return r;
}

// Coalesced pre (verified R8). Bf[c][k] = bf16(0.125*(cl@Wk@Wq^T)[c][k]),
// Bf[c][64+d] = bf16((cl@Wv)[c][d]).
__global__ __launch_bounds__(256) void pre(const float* __restrict__ cl,
                                           const float* __restrict__ Wk,
                                           const float* __restrict__ Wq,
                                           const float* __restrict__ Wv,
                                           short* __restrict__ Bf) {
  __shared__ float s_cl[4 * 64];
  __shared__ float s_kc[4 * 64];
  __shared__ float s_w[64 * 65];
  const int t = threadIdx.x;
  const int bh = blockIdx.x >> 6, cb = blockIdx.x & 63;
  const int c0 = cb * 4;
  const int r = t >> 6, j = t & 63;

  s_cl[t] = cl[c0 * 64 + t];
  if (bh == 0) {
#pragma unroll
    for (int i = 0; i < 4; ++i) {
      int e = i * 256 + t;
      float4 v = ((const float4*)Wq)[e];
      int k = e >> 4, q = e & 15;
      float* dst = &s_w[k * 65 + q * 4];
      dst[0] = v.x; dst[1] = v.y; dst[2] = v.z; dst[3] = v.w;
    }
  }
  __syncthreads();

  const float* __restrict__ Wx = bh ? Wv : Wk;
  float acc = 0.f;
#pragma unroll 8
  for (int m = 0; m < 64; ++m) acc += s_cl[r * 64 + m] * Wx[m * 64 + j];

  if (bh == 1) {
    Bf[(c0 + r) * 128 + 64 + j] = f2bf(acc);
    return;
  }
  s_kc[t] = acc;
  __syncthreads();

  float o = 0.f;
#pragma unroll 8
  for (int jj = 0; jj < 64; ++jj) o += s_kc[r * 64 + jj] * s_w[j * 65 + jj];
  Bf[(c0 + r) * 128 + j] = f2bf(0.125f * o);
}

// Sum one s2 row (64 float2 partials) across 4 chunk-lanes.
__device__ inline float reduce_row(const float2* __restrict__ rowp, int chunk) {
  float sx = 0.f, sy = 0.f;
#pragma unroll
  for (int j = 0; j < 8; ++j) {
    int jr = (j + chunk) & 7;
    float4 v = *(const float4*)&rowp[chunk * 16 + jr * 2];
    sx += v.x + v.z;
    sy += v.y + v.w;
  }
  sx += __shfl_xor(sx, 1, 64);
  sy += __shfl_xor(sy, 1, 64);
  sx += __shfl_xor(sx, 2, 64);
  sy += __shfl_xor(sy, 2, 64);
  return sy * __frcp_rn(sx);  // s_l = T/S, valid in chunk==0 lanes
}

__device__ inline float bcast(float v, int srclane) {
  return __uint_as_float(__builtin_amdgcn_readlane(__float_as_uint(v), srclane));
}

// R20: straight G=4 port of R18 (no pipelining). 1024 blocks -> 4/CU.
// Zero-shuffle packing, exact at G=4 (verified in R19):
//   A row r=col16: g = qr, l = mt*4 + jr (zero if l>=10)
//   au row col16 -> user col16>>2 (4x duplicated)
//   C/D row kb*4+jj: g = kb, l = mt*4 + jj; vu = own cu[0] (user kb)
//   s2 row = kb*10 + l; transpose-reduce: wave w owns user w.
__global__ __launch_bounds__(256) void filter_main(
    const int* __restrict__ items, const float* __restrict__ te,
    const float* __restrict__ ue_g, const float* __restrict__ ie_g,
    const float* __restrict__ wf_g, const short* __restrict__ Bf,
    const int* __restrict__ users, const int* __restrict__ pos_items,
    const int* __restrict__ neg_items, const float* __restrict__ a1p,
    const float* __restrict__ a2p, const float* __restrict__ a3p,
    float* __restrict__ out, int B) {
  __shared__ short s_shb[44 * SWB];  // 40 short rows + 4 ue rows, bf16
  __shared__ float2 s2[40 * ST];     // raw (S,T) partials [row][64 cols]

  const int tid = threadIdx.x, w = tid >> 6, lane = tid & 63;
  const int col16 = lane & 15, kb = lane >> 4;
  const int qr = col16 >> 2, jr = col16 & 3;
  const int b4 = blockIdx.x * G;
  const int BD = B * D;

  // hoisted per-user long-latency loads: wave w owns user w
  const int uA = users[b4 + w];
  const float uevA = ue_g[uA * D + lane];
  const float posvA = ie_g[pos_items[b4 + w] * D + lane];
  const float negvA = ie_g[neg_items[b4 + w] * D + lane];
  float wfvA[L];
#pragma unroll
  for (int l = 0; l < L; ++l) wfvA[l] = wf_g[(uA * L + l) * D + lane];

  // ---- coalesced staging: 40 short rows + 4 ue rows -> bf16 LDS
  {
    const float4* te4 = (const float4*)te;
    const float4* ie4 = (const float4*)ie_g;
    const float4* ue4 = (const float4*)ue_g;
    const int grp = tid >> 4, j = tid & 15;
#pragma unroll
    for (int it = 0; it < 3; ++it) {
      int row = it * 16 + grp;
      if (row < 40) {
        int g = row / 10, l = row - g * 10;
        int u = users[b4 + g];
        int itm = items[u * L + l];
        float4 v = add3(te4[(u * L + l) * 16 + j], ie4[itm * 16 + j],
                        ue4[u * 16 + j]);
        *(short4v*)&s_shb[row * SWB + j * 4] = f2bf4(v);
      } else if (row < 44) {
        int u = users[b4 + (row - 40)];
        *(short4v*)&s_shb[row * SWB + j * 4] = f2bf4(ue4[u * 16 + j]);
      }
    }
  }
  __syncthreads();

  // ---- A fragments: g = qr, l = mt*4 + jr; au row -> user qr (4x dup)
  bf16x8 af[3][2];
  bf16x8 au0, au1;
#pragma unroll
  for (int mt = 0; mt < 3; ++mt) {
    int l = mt * 4 + jr;
    if (l < L) {
      const bf16x8* rp = (const bf16x8*)&s_shb[(qr * 10 + l) * SWB];
      af[mt][0] = rp[kb];
      af[mt][1] = rp[4 + kb];
    } else {
      af[mt][0] = bf16x8{};
      af[mt][1] = bf16x8{};
    }
  }
  {
    const bf16x8* rp = (const bf16x8*)&s_shb[(40 + qr) * SWB];
    au0 = rp[kb];
    au1 = rp[4 + kb];
  }

  // ---- per-nt GEMM + softmax accumulation (no max-sub; fp32-safe range)
  float Sa[3][4], Ta[3][4];
#pragma unroll
  for (int mt = 0; mt < 3; ++mt)
#pragma unroll
    for (int jj = 0; jj < 4; ++jj) { Sa[mt][jj] = 0.f; Ta[mt][jj] = 0.f; }

#pragma unroll
  for (int nt = 0; nt < 4; ++nt) {
    const bf16x8* bp = (const bf16x8*)(Bf + ((w * 4 + nt) * 16 + col16) * 128);
    bf16x8 b0 = bp[kb], b1 = bp[4 + kb], b2 = bp[8 + kb], b3 = bp[12 + kb];
    f32x4 z = {0.f, 0.f, 0.f, 0.f};
    f32x4 cc[3];
    f32x4 cu = z;
#pragma unroll
    for (int mt = 0; mt < 3; ++mt) {
      cc[mt] = z;
      cc[mt] = __builtin_amdgcn_mfma_f32_16x16x32_bf16(af[mt][0], b0, cc[mt], 0, 0, 0);
      cc[mt] = __builtin_amdgcn_mfma_f32_16x16x32_bf16(af[mt][1], b1, cc[mt], 0, 0, 0);
    }
    cu = __builtin_amdgcn_mfma_f32_16x16x32_bf16(au0, b2, cu, 0, 0, 0);
    cu = __builtin_amdgcn_mfma_f32_16x16x32_bf16(au1, b3, cu, 0, 0, 0);
    const float vuv = cu[0];  // user kb for every score this lane owns
#pragma unroll
    for (int mt = 0; mt < 3; ++mt)
#pragma unroll
      for (int jj = 0; jj < 4; ++jj) {
        if (mt * 4 + jj < L) {
          float e = __expf(cc[mt][jj]);
          Sa[mt][jj] += e;
          Ta[mt][jj] += e * vuv;
        }
      }
  }

  // ---- write raw per-lane partials to s2[row = kb*10 + l][w*16+col16]
#pragma unroll
  for (int mt = 0; mt < 3; ++mt)
#pragma unroll
    for (int jj = 0; jj < 4; ++jj) {
      const int l = mt * 4 + jj;
      if (l < L)
        s2[(kb * 10 + l) * ST + w * 16 + col16] =
            make_float2(Sa[mt][jj], Ta[mt][jj]);
    }
  __syncthreads();

  // ---- transpose-reduce: wave w owns user w
  const int slot = lane >> 2, chunk = lane & 3;
  int rowA = w * 10 + ((slot < 10) ? slot : 0);
  float slv = reduce_row(&s2[rowA * ST], chunk);

  // ---- broadcast s_l via v_readlane (SALU), accumulate nu
  float nuA = 0.f;
#pragma unroll
  for (int l = 0; l < L; ++l) nuA += bcast(slv, l * 4) * wfvA[l];

  const float a1 = *a1p, a2 = *a2p, a3 = *a3p;
  out[(b4 + w) * D + lane] = a3 * (a1 * uevA + a2 * nuA);
  out[BD + (b4 + w) * D + lane] = posvA;
  out[2 * BD + (b4 + w) * D + lane] = negvA;
}

extern "C" void kernel_launch(void* const* d_in, const int* in_sizes, int n_in,
                              void* d_out, int out_size, void* d_ws, size_t ws_size,
                              hipStream_t stream) {
  const int* items = (const int*)d_in[0];
  const float* time_embs = (const float*)d_in[1];
  const float* user_emb = (const float*)d_in[2];
  const float* item_emb = (const float*)d_in[3];
  const float* cluster = (const float*)d_in[4];
  const float* wf = (const float*)d_in[5];
  const float* Wq = (const float*)d_in[6];
  const float* Wk = (const float*)d_in[7];
  const float* Wv = (const float*)d_in[8];
  const int* users = (const int*)d_in[9];
  const int* pos = (const int*)d_in[10];
  const int* neg = (const int*)d_in[11];
  const float* a1 = (const float*)d_in[12];
  const float* a2 = (const float*)d_in[13];
  const float* a3 = (const float*)d_in[14];
  const int B = in_sizes[9];

  short* Bf = (short*)d_ws;  // [C][128] bf16
  hipLaunchKernelGGL(pre, dim3(128), dim3(256), 0, stream,
                     cluster, Wk, Wq, Wv, Bf);
  hipLaunchKernelGGL(filter_main, dim3(B / G), dim3(256), 0, stream,
                     items, time_embs, user_emb, item_emb, wf, Bf,
                     users, pos, neg, a1, a2, a3, (float*)d_out, B);
}

// Round 21
// 23.214 us; speedup vs baseline: 1.2212x; 1.2212x over previous
//
#include <hip/hip_runtime.h>

#define D 64
#define L 10
#define C 256
#define G 8
#define SWB 72  // bf16 LDS row stride in shorts (144 B, 16B-aligned)
#define ST 66   // s2 row stride in float2 (528 B; +4-bank shift per row)

typedef __attribute__((ext_vector_type(8))) short bf16x8;
typedef __attribute__((ext_vector_type(4))) short short4v;
typedef __attribute__((ext_vector_type(4))) float f32x4;

__device__ inline short f2bf(float f) {
  unsigned u = __float_as_uint(f);
  u = (u + 0x7FFFu + ((u >> 16) & 1u)) >> 16;
  return (short)u;
}
__device__ inline float4 add3(float4 a, float4 b, float4 c) {
  return make_float4(a.x + b.x + c.x, a.y + b.y + c.y, a.z + b.z + c.z, a.w + b.w + c.w);
}
__device__ inline short4v f2bf4(float4 a) {
  short4v r;
  r[0] = f2bf(a.x); r[1] = f2bf(a.y); r[2] = f2bf(a.z); r[3] = f2bf(a.w);
  return r;
}

// Coalesced pre (verified R8). Bf[c][k] = bf16(0.125*(cl@Wk@Wq^T)[c][k]),
// Bf[c][64+d] = bf16((cl@Wv)[c][d]).
__global__ __launch_bounds__(256) void pre(const float* __restrict__ cl,
                                           const float* __restrict__ Wk,
                                           const float* __restrict__ Wq,
                                           const float* __restrict__ Wv,
                                           short* __restrict__ Bf) {
  __shared__ float s_cl[4 * 64];
  __shared__ float s_kc[4 * 64];
  __shared__ float s_w[64 * 65];
  const int t = threadIdx.x;
  const int bh = blockIdx.x >> 6, cb = blockIdx.x & 63;
  const int c0 = cb * 4;
  const int r = t >> 6, j = t & 63;

  s_cl[t] = cl[c0 * 64 + t];
  if (bh == 0) {
#pragma unroll
    for (int i = 0; i < 4; ++i) {
      int e = i * 256 + t;
      float4 v = ((const float4*)Wq)[e];
      int k = e >> 4, q = e & 15;
      float* dst = &s_w[k * 65 + q * 4];
      dst[0] = v.x; dst[1] = v.y; dst[2] = v.z; dst[3] = v.w;
    }
  }
  __syncthreads();

  const float* __restrict__ Wx = bh ? Wv : Wk;
  float acc = 0.f;
#pragma unroll 8
  for (int m = 0; m < 64; ++m) acc += s_cl[r * 64 + m] * Wx[m * 64 + j];

  if (bh == 1) {
    Bf[(c0 + r) * 128 + 64 + j] = f2bf(acc);
    return;
  }
  s_kc[t] = acc;
  __syncthreads();

  float o = 0.f;
#pragma unroll 8
  for (int jj = 0; jj < 64; ++jj) o += s_kc[r * 64 + jj] * s_w[j * 65 + jj];
  Bf[(c0 + r) * 128 + j] = f2bf(0.125f * o);
}

// Sum one s2 row (64 float2 partials) across 4 chunk-lanes.
__device__ inline float reduce_row(const float2* __restrict__ rowp, int chunk) {
  float sx = 0.f, sy = 0.f;
#pragma unroll
  for (int j = 0; j < 8; ++j) {
    int jr = (j + chunk) & 7;
    float4 v = *(const float4*)&rowp[chunk * 16 + jr * 2];
    sx += v.x + v.z;
    sy += v.y + v.w;
  }
  sx += __shfl_xor(sx, 1, 64);
  sy += __shfl_xor(sy, 1, 64);
  sx += __shfl_xor(sx, 2, 64);
  sy += __shfl_xor(sy, 2, 64);
  return sy * __frcp_rn(sx);  // s_l = T/S, valid in chunk==0 lanes
}

__device__ inline float bcast(float v, int srclane) {
  return __uint_as_float(__builtin_amdgcn_readlane(__float_as_uint(v), srclane));
}

// R18 packing (zero-shuffle vu): slot p = kb*6 + mt.
//   A row r (= C/D row): user g = 2*(r>>2) + mt/3, l = (mt%3)*4 + (r&3).
//   au tile row r -> ue[user r>>1] (each user duplicated in 2 rows), so
//   cu reg jj at lane-group kb holds vu[2kb + (jj>>1)]; the vu for every
//   score this lane owns at tile mt is its OWN cu[2*(mt/3)] — no bpermute.
// Downstream s2 transpose-reduce identical to R16 (row = g*10 + l).
__global__ __launch_bounds__(256) void filter_main(
    const int* __restrict__ items, const float* __restrict__ te,
    const float* __restrict__ ue_g, const float* __restrict__ ie_g,
    const float* __restrict__ wf_g, const short* __restrict__ Bf,
    const int* __restrict__ users, const int* __restrict__ pos_items,
    const int* __restrict__ neg_items, const float* __restrict__ a1p,
    const float* __restrict__ a2p, const float* __restrict__ a3p,
    float* __restrict__ out, int B) {
  __shared__ short s_shb[88 * SWB];  // 80 short rows + 8 ue rows, bf16
  __shared__ float2 s2[80 * ST];     // raw (S,T) partials [row][64 cols]

  const int tid = threadIdx.x, w = tid >> 6, lane = tid & 63;
  const int col16 = lane & 15, kb = lane >> 4;
  const int qr = col16 >> 2, jr = col16 & 3;
  const int b8 = blockIdx.x * G;
  const int BD = B * D;

  // hoisted per-user long-latency loads: wave w owns users w and w+4
  const int uA = users[b8 + w], uB = users[b8 + 4 + w];
  const float uevA = ue_g[uA * D + lane];
  const float uevB = ue_g[uB * D + lane];
  const float posvA = ie_g[pos_items[b8 + w] * D + lane];
  const float posvB = ie_g[pos_items[b8 + 4 + w] * D + lane];
  const float negvA = ie_g[neg_items[b8 + w] * D + lane];
  const float negvB = ie_g[neg_items[b8 + 4 + w] * D + lane];
  float wfvA[L], wfvB[L];
#pragma unroll
  for (int l = 0; l < L; ++l) {
    wfvA[l] = wf_g[(uA * L + l) * D + lane];
    wfvB[l] = wf_g[(uB * L + l) * D + lane];
  }

  // ---- coalesced staging: 80 short rows + 8 ue rows -> bf16 LDS
  {
    const float4* te4 = (const float4*)te;
    const float4* ie4 = (const float4*)ie_g;
    const float4* ue4 = (const float4*)ue_g;
    const int grp = tid >> 4, j = tid & 15;
#pragma unroll
    for (int it = 0; it < 6; ++it) {
      int row = it * 16 + grp;
      if (row < 80) {
        int g = row / 10, l = row - g * 10;
        int u = users[b8 + g];
        int itm = items[u * L + l];
        float4 v = add3(te4[(u * L + l) * 16 + j], ie4[itm * 16 + j],
                        ue4[u * 16 + j]);
        *(short4v*)&s_shb[row * SWB + j * 4] = f2bf4(v);
      } else if (row < 88) {
        int u = users[b8 + (row - 80)];
        *(short4v*)&s_shb[row * SWB + j * 4] = f2bf4(ue4[u * 16 + j]);
      }
    }
  }
  __syncthreads();

  // ---- A fragments (R18 packing): row r=col16 -> g = 2*qr + mt/3,
  //      l = (mt%3)*4 + jr  (l>=10 rows zero, compile-time per (mt, jr))
  bf16x8 af[6][2];
  bf16x8 au0, au1;
#pragma unroll
  for (int mt = 0; mt < 6; ++mt) {
    int g = 2 * qr + mt / 3;
    int l = (mt % 3) * 4 + jr;
    if (l < L) {
      const bf16x8* rp = (const bf16x8*)&s_shb[(g * 10 + l) * SWB];
      af[mt][0] = rp[kb];
      af[mt][1] = rp[4 + kb];
    } else {
      af[mt][0] = bf16x8{};
      af[mt][1] = bf16x8{};
    }
  }
  {  // au row col16 -> user col16>>1 (duplicated)
    const bf16x8* rp = (const bf16x8*)&s_shb[(80 + (col16 >> 1)) * SWB];
    au0 = rp[kb];
    au1 = rp[4 + kb];
  }

  // ---- per-nt GEMM + softmax accumulation (no max-sub; fp32-safe range)
  float Sa[6][4], Ta[6][4];
#pragma unroll
  for (int mt = 0; mt < 6; ++mt)
#pragma unroll
    for (int jj = 0; jj < 4; ++jj) { Sa[mt][jj] = 0.f; Ta[mt][jj] = 0.f; }

#pragma unroll
  for (int nt = 0; nt < 4; ++nt) {
    const bf16x8* bp = (const bf16x8*)(Bf + ((w * 4 + nt) * 16 + col16) * 128);
    bf16x8 b0 = bp[kb], b1 = bp[4 + kb], b2 = bp[8 + kb], b3 = bp[12 + kb];
    f32x4 z = {0.f, 0.f, 0.f, 0.f};
    f32x4 cc[6];
    f32x4 cu = z;
#pragma unroll
    for (int mt = 0; mt < 6; ++mt) {
      cc[mt] = z;
      cc[mt] = __builtin_amdgcn_mfma_f32_16x16x32_bf16(af[mt][0], b0, cc[mt], 0, 0, 0);
      cc[mt] = __builtin_amdgcn_mfma_f32_16x16x32_bf16(af[mt][1], b1, cc[mt], 0, 0, 0);
    }
    cu = __builtin_amdgcn_mfma_f32_16x16x32_bf16(au0, b2, cu, 0, 0, 0);
    cu = __builtin_amdgcn_mfma_f32_16x16x32_bf16(au1, b3, cu, 0, 0, 0);
    // vu for this lane's scores at tile mt = own cu[2*(mt/3)] (no shuffle)
#pragma unroll
    for (int mt = 0; mt < 6; ++mt) {
      const float vuv = (mt < 3) ? cu[0] : cu[2];
#pragma unroll
      for (int jj = 0; jj < 4; ++jj) {
        if ((mt % 3) * 4 >= L && jj >= 2) continue;  // l>=10: dead slot
        float e = __expf(cc[mt][jj]);
        Sa[mt][jj] += e;
        Ta[mt][jj] += e * vuv;
      }
    }
  }

  // ---- write raw per-lane partials to s2[row = g*10+l][w*16+col16]
  //      g = 2*kb + mt/3, l = (mt%3)*4 + jj  (l<10 compile-time predicate)
#pragma unroll
  for (int mt = 0; mt < 6; ++mt)
#pragma unroll
    for (int jj = 0; jj < 4; ++jj) {
      const int l = (mt % 3) * 4 + jj;
      if (l < L) {
        int g = 2 * kb + mt / 3;
        s2[(g * 10 + l) * ST + w * 16 + col16] =
            make_float2(Sa[mt][jj], Ta[mt][jj]);
      }
    }
  __syncthreads();

  // ---- transpose-reduce: wave w sums rows of users w (A) and w+4 (B)
  const int slot = lane >> 2, chunk = lane & 3;
  int rowA = (slot < 10) ? (w * 10 + slot) : ((w + 4) * 10 + (slot - 10));
  float slA_v = reduce_row(&s2[rowA * ST], chunk);
  int rowB = (slot < 4) ? ((w + 4) * 10 + 6 + slot) : 0;
  float slB_v = reduce_row(&s2[rowB * ST], chunk);

  // ---- broadcast s_l via v_readlane (SALU), accumulate nu
  float nuA = 0.f, nuB = 0.f;
#pragma unroll
  for (int l = 0; l < L; ++l) {
    nuA += bcast(slA_v, l * 4) * wfvA[l];
    float sb = (l < 6) ? bcast(slA_v, (10 + l) * 4) : bcast(slB_v, (l - 6) * 4);
    nuB += sb * wfvB[l];
  }

  const float a1 = *a1p, a2 = *a2p, a3 = *a3p;
  out[(b8 + w) * D + lane] = a3 * (a1 * uevA + a2 * nuA);
  out[(b8 + 4 + w) * D + lane] = a3 * (a1 * uevB + a2 * nuB);
  out[BD + (b8 + w) * D + lane] = posvA;
  out[BD + (b8 + 4 + w) * D + lane] = posvB;
  out[2 * BD + (b8 + w) * D + lane] = negvA;
  out[2 * BD + (b8 + 4 + w) * D + lane] = negvB;
}

extern "C" void kernel_launch(void* const* d_in, const int* in_sizes, int n_in,
                              void* d_out, int out_size, void* d_ws, size_t ws_size,
                              hipStream_t stream) {
  const int* items = (const int*)d_in[0];
  const float* time_embs = (const float*)d_in[1];
  const float* user_emb = (const float*)d_in[2];
  const float* item_emb = (const float*)d_in[3];
  const float* cluster = (const float*)d_in[4];
  const float* wf = (const float*)d_in[5];
  const float* Wq = (const float*)d_in[6];
  const float* Wk = (const float*)d_in[7];
  const float* Wv = (const float*)d_in[8];
  const int* users = (const int*)d_in[9];
  const int* pos = (const int*)d_in[10];
  const int* neg = (const int*)d_in[11];
  const float* a1 = (const float*)d_in[12];
  const float* a2 = (const float*)d_in[13];
  const float* a3 = (const float*)d_in[14];
  const int B = in_sizes[9];

  short* Bf = (short*)d_ws;  // [C][128] bf16
  hipLaunchKernelGGL(pre, dim3(128), dim3(256), 0, stream,
                     cluster, Wk, Wq, Wv, Bf);
  hipLaunchKernelGGL(filter_main, dim3(B / G), dim3(256), 0, stream,
                     items, time_embs, user_emb, item_emb, wf, Bf,
                     users, pos, neg, a1, a2, a3, (float*)d_out, B);
}